// Round 6
// baseline (361.842 us; speedup 1.0000x reference)
//
#include <hip/hip_runtime.h>

typedef __attribute__((ext_vector_type(8))) short short8;
typedef __attribute__((ext_vector_type(4))) float f32x4;

#define GLOAD16(gp, lp)                                                        \
  __builtin_amdgcn_global_load_lds(                                            \
      (const __attribute__((address_space(1))) void*)(gp),                     \
      (__attribute__((address_space(3))) void*)(lp), 16, 0, 0)

__device__ __forceinline__ unsigned short f2bf(float f) {
  unsigned int u = __builtin_bit_cast(unsigned int, f);
  u += 0x7fffu + ((u >> 16) & 1u);
  return (unsigned short)(u >> 16);
}

// ---------------- f32 -> bf16 convert (vectorized, optional scale) ---------
__global__ __launch_bounds__(256) void cvt_f32_bf16(
    const float* __restrict__ src, unsigned short* __restrict__ dst, int n,
    float scale) {
  int i = (blockIdx.x * 256 + threadIdx.x) * 8;
  if (i + 8 <= n) {
    float4 a = *(const float4*)(src + i);
    float4 b = *(const float4*)(src + i + 4);
    short8 r;
    r[0] = (short)f2bf(a.x * scale); r[1] = (short)f2bf(a.y * scale);
    r[2] = (short)f2bf(a.z * scale); r[3] = (short)f2bf(a.w * scale);
    r[4] = (short)f2bf(b.x * scale); r[5] = (short)f2bf(b.y * scale);
    r[6] = (short)f2bf(b.z * scale); r[7] = (short)f2bf(b.w * scale);
    *(short8*)(dst + i) = r;
  }
}

// ---------------- NT GEMM 256xBN, 2-phase double-buffered ----------------
// C[M,N] = A[M,K] * B[N,K]^T. 512 threads = 8 waves (2M x 4N).
// Per-wave tile: 128 x (BN/4). T3-minimum recipe: stage next tile into the
// opposite LDS buffer, one __syncthreads per K-tile. XCD-swizzled 1D grid.
template <int BN, int OUTF32>
__global__ __launch_bounds__(512) void gemm_nt2(
    const unsigned short* __restrict__ A, const unsigned short* __restrict__ B,
    void* __restrict__ Cout, const float* __restrict__ bias, int M, int N,
    int K, int nwg_y) {
  constexpr int NF = BN / 64;     // per-wave n fragments
  constexpr int WNSZ = BN / 4;    // per-wave N span
  __shared__ __align__(16) unsigned short As[2][256][64];
  __shared__ __align__(16) unsigned short Bs[2][BN][64];

  // XCD-aware bijective swizzle (nwg % 8 == 0 guaranteed by launch config)
  const int nwg = gridDim.x;
  const int id = blockIdx.x;
  const int sw = (id & 7) * (nwg >> 3) + (id >> 3);
  const int bx = sw / nwg_y, by = sw % nwg_y;  // A-panel reused within chunk
  const int row0 = bx * 256, col0 = by * BN;

  const int tid = threadIdx.x;
  const int wave = tid >> 6, lane = tid & 63;
  const int wm = wave >> 2, wn = wave & 3;
  const int l15 = lane & 15, l16 = lane >> 4;
  const int lrow = lane >> 3, lcol = (lane & 7) * 8;
  const int wv8 = wave * 8;

  f32x4 acc[8][NF];
#pragma unroll
  for (int m = 0; m < 8; ++m)
#pragma unroll
    for (int n = 0; n < NF; ++n) acc[m][n] = f32x4{0.f, 0.f, 0.f, 0.f};

  const int nt = K >> 6;

#define STAGE_TILE(buf, k0)                                                    \
  {                                                                            \
    _Pragma("unroll") for (int j = 0; j < 4; ++j) {                            \
      const unsigned short* gp =                                               \
          A + (size_t)(row0 + j * 64 + wv8 + lrow) * K + (k0) + lcol;          \
      GLOAD16(gp, &As[buf][j * 64 + wv8][0]);                                  \
    }                                                                          \
    _Pragma("unroll") for (int j = 0; j < NF; ++j) {                           \
      const unsigned short* gp =                                               \
          B + (size_t)(col0 + j * 64 + wv8 + lrow) * K + (k0) + lcol;          \
      GLOAD16(gp, &Bs[buf][j * 64 + wv8][0]);                                  \
    }                                                                          \
  }

  // prologue: stage tile 0
  STAGE_TILE(0, 0)
  __syncthreads();

  for (int t = 0; t < nt; ++t) {
    const int cur = t & 1;
    if (t + 1 < nt) STAGE_TILE(cur ^ 1, (t + 1) << 6)

#pragma unroll
    for (int kk = 0; kk < 2; ++kk) {
      short8 a[8], b[NF];
#pragma unroll
      for (int m = 0; m < 8; ++m)
        a[m] = *(const short8*)&As[cur][wm * 128 + m * 16 + l15][kk * 32 + l16 * 8];
#pragma unroll
      for (int n = 0; n < NF; ++n)
        b[n] = *(const short8*)&Bs[cur][wn * WNSZ + n * 16 + l15][kk * 32 + l16 * 8];
#pragma unroll
      for (int m = 0; m < 8; ++m)
#pragma unroll
        for (int n = 0; n < NF; ++n)
          acc[m][n] =
              __builtin_amdgcn_mfma_f32_16x16x32_bf16(a[m], b[n], acc[m][n], 0, 0, 0);
    }
    __syncthreads();  // drains vmcnt (stage) + lgkm; protects both buffers
  }

#pragma unroll
  for (int m = 0; m < 8; ++m) {
    const int row = row0 + wm * 128 + m * 16 + l16 * 4;
#pragma unroll
    for (int n = 0; n < NF; ++n) {
      const int col = col0 + wn * WNSZ + n * 16 + l15;
      float bv = 0.f;
      if (OUTF32) bv = bias[col];
#pragma unroll
      for (int r = 0; r < 4; ++r) {
        const float v = acc[m][n][r] + bv;
        if (OUTF32)
          ((float*)Cout)[(size_t)(row + r) * N + col] = v;
        else
          ((unsigned short*)Cout)[(size_t)(row + r) * N + col] = f2bf(v);
      }
    }
  }
#undef STAGE_TILE
}

// ---------------- causal flash attention (unchanged from R4) ----------------
__global__ __launch_bounds__(256) void attn_fwd(
    const unsigned short* __restrict__ QKV, unsigned short* __restrict__ AO) {
  const int S = 2048, LD = 3072;
  const int qt = gridDim.x - 1 - blockIdx.x;
  const int bh = blockIdx.y, b = bh >> 4, h = bh & 15;
  const int tid = threadIdx.x, wave = tid >> 6, lane = tid & 63;
  const int l15 = lane & 15, l16 = lane >> 4;
  const int q0 = qt * 64;

  __shared__ __align__(16) char KsB[2][64 * 128];
  __shared__ __align__(16) char VTB[2][64 * 128];
  __shared__ __align__(16) char PlB[4][16 * 128];

  const unsigned short* qptr =
      QKV + (size_t)(b * S + q0 + wave * 16 + l15) * LD + h * 64 + l16 * 8;
  short8 qf[2];
  qf[0] = *(const short8*)(qptr);
  qf[1] = *(const short8*)(qptr + 32);

  const int krow = lane >> 3;
  const int kcol = (((lane & 7) ^ (lane >> 3)) & 7) * 8;
  const int vp_ = tid & 31, vd0 = (tid >> 5) * 8;

  float mrow = -1e30f, lsum = 0.f;
  f32x4 accO[4] = {};
  const int nkv = qt + 1;

  {
#pragma unroll
    for (int i = 0; i < 2; ++i) {
      const int c = i * 4 + wave;
      const unsigned short* gp =
          QKV + (size_t)(b * S + c * 8 + krow) * LD + 1024 + h * 64 + kcol;
      GLOAD16(gp, KsB[0] + c * 1024);
    }
    const unsigned short* vp =
        QKV + (size_t)(b * S + 2 * vp_) * LD + 2048 + h * 64 + vd0;
    short8 va = *(const short8*)vp;
    short8 vb = *(const short8*)(vp + LD);
    uint4 vaw = __builtin_bit_cast(uint4, va);
    uint4 vbw = __builtin_bit_cast(uint4, vb);
    const unsigned int aw[4] = {vaw.x, vaw.y, vaw.z, vaw.w};
    const unsigned int bw[4] = {vbw.x, vbw.y, vbw.z, vbw.w};
#pragma unroll
    for (int w = 0; w < 4; ++w) {
      unsigned int e = __builtin_amdgcn_perm(bw[w], aw[w], 0x05040100u);
      unsigned int o = __builtin_amdgcn_perm(bw[w], aw[w], 0x07060302u);
      *(unsigned int*)(VTB[0] + (((vd0 + 2 * w) * 128 + 4 * vp_) ^ ((2 * w) << 4))) = e;
      *(unsigned int*)(VTB[0] + (((vd0 + 2 * w + 1) * 128 + 4 * vp_) ^ ((2 * w + 1) << 4))) = o;
    }
  }
  __syncthreads();

  for (int t = 0; t < nkv; ++t) {
    const int cur = t & 1, kv0 = t * 64;

    f32x4 accS[4] = {};
#pragma unroll
    for (int sub = 0; sub < 4; ++sub) {
      const int rw = sub * 16 + l15;
#pragma unroll
      for (int kk = 0; kk < 2; ++kk) {
        short8 kf = *(const short8*)(KsB[cur] + rw * 128 +
                                     ((kk * 64 + l16 * 16) ^ ((l15 & 7) << 4)));
        accS[sub] =
            __builtin_amdgcn_mfma_f32_16x16x32_bf16(kf, qf[kk], accS[sub], 0, 0, 0);
      }
    }

    short8 va, vb;
    const bool pre = (t + 1 < nkv);
    if (pre) {
      const int kvn = kv0 + 64;
#pragma unroll
      for (int i = 0; i < 2; ++i) {
        const int c = i * 4 + wave;
        const unsigned short* gp =
            QKV + (size_t)(b * S + kvn + c * 8 + krow) * LD + 1024 + h * 64 + kcol;
        GLOAD16(gp, KsB[cur ^ 1] + c * 1024);
      }
      const unsigned short* vp =
          QKV + (size_t)(b * S + kvn + 2 * vp_) * LD + 2048 + h * 64 + vd0;
      va = *(const short8*)vp;
      vb = *(const short8*)(vp + LD);
    }

    const bool nm = (kv0 + 63 > q0 + wave * 16);
    float mx = -1e30f;
    if (nm) {
      const int qabs = q0 + wave * 16 + l15;
#pragma unroll
      for (int sub = 0; sub < 4; ++sub)
#pragma unroll
        for (int r = 0; r < 4; ++r) {
          float s = accS[sub][r];
          if (kv0 + sub * 16 + l16 * 4 + r > qabs) s = -1e30f;
          accS[sub][r] = s;
          mx = fmaxf(mx, s);
        }
    } else {
#pragma unroll
      for (int sub = 0; sub < 4; ++sub)
#pragma unroll
        for (int r = 0; r < 4; ++r) mx = fmaxf(mx, accS[sub][r]);
    }
    mx = fmaxf(mx, __shfl_xor(mx, 16));
    mx = fmaxf(mx, __shfl_xor(mx, 32));

    if (__any(mx > mrow + 8.0f)) {
      const float mnew = fmaxf(mrow, mx);
      const float alpha = exp2f(mrow - mnew);
      mrow = mnew;
      lsum *= alpha;
      float al[4];
#pragma unroll
      for (int r = 0; r < 4; ++r) al[r] = __shfl(alpha, l16 * 4 + r);
#pragma unroll
      for (int sd = 0; sd < 4; ++sd)
#pragma unroll
        for (int r = 0; r < 4; ++r) accO[sd][r] *= al[r];
    }

    float rs = 0.f;
#pragma unroll
    for (int sub = 0; sub < 4; ++sub) {
      float p0 = exp2f(accS[sub][0] - mrow);
      float p1 = exp2f(accS[sub][1] - mrow);
      float p2 = exp2f(accS[sub][2] - mrow);
      float p3 = exp2f(accS[sub][3] - mrow);
      rs += (p0 + p1) + (p2 + p3);
      unsigned int pk01, pk23;
      asm("v_cvt_pk_bf16_f32 %0, %1, %2" : "=v"(pk01) : "v"(p0), "v"(p1));
      asm("v_cvt_pk_bf16_f32 %0, %1, %2" : "=v"(pk23) : "v"(p2), "v"(p3));
      uint2 pw = {pk01, pk23};
      *(uint2*)(PlB[wave] +
                ((l15 * 128 + sub * 32 + l16 * 8) ^ ((l15 & 7) << 4))) = pw;
    }
    rs += __shfl_xor(rs, 16);
    rs += __shfl_xor(rs, 32);
    lsum += rs;

    if (pre) {
      uint4 vaw = __builtin_bit_cast(uint4, va);
      uint4 vbw = __builtin_bit_cast(uint4, vb);
      const unsigned int aw[4] = {vaw.x, vaw.y, vaw.z, vaw.w};
      const unsigned int bw[4] = {vbw.x, vbw.y, vbw.z, vbw.w};
#pragma unroll
      for (int w = 0; w < 4; ++w) {
        unsigned int e = __builtin_amdgcn_perm(bw[w], aw[w], 0x05040100u);
        unsigned int o = __builtin_amdgcn_perm(bw[w], aw[w], 0x07060302u);
        *(unsigned int*)(VTB[cur ^ 1] +
                         (((vd0 + 2 * w) * 128 + 4 * vp_) ^ ((2 * w) << 4))) = e;
        *(unsigned int*)(VTB[cur ^ 1] +
                         (((vd0 + 2 * w + 1) * 128 + 4 * vp_) ^ ((2 * w + 1) << 4))) = o;
      }
    }

#pragma unroll
    for (int kk = 0; kk < 2; ++kk) {
      short8 pf = *(const short8*)(PlB[wave] + ((l15 * 128 + kk * 64 + l16 * 16) ^
                                               ((l15 & 7) << 4)));
#pragma unroll
      for (int sd = 0; sd < 4; ++sd) {
        short8 vf = *(const short8*)(VTB[cur] + (sd * 16 + l15) * 128 +
                                     ((kk * 64 + l16 * 16) ^ ((l15 & 7) << 4)));
        accO[sd] =
            __builtin_amdgcn_mfma_f32_16x16x32_bf16(pf, vf, accO[sd], 0, 0, 0);
      }
    }
    __syncthreads();
  }

  float ls[4];
#pragma unroll
  for (int r = 0; r < 4; ++r) ls[r] = __shfl(lsum, l16 * 4 + r);
#pragma unroll
  for (int sd = 0; sd < 4; ++sd)
#pragma unroll
    for (int r = 0; r < 4; ++r) {
      AO[(size_t)(b * S + q0 + wave * 16 + l16 * 4 + r) * 1024 + h * 64 +
         sd * 16 + l15] = f2bf(accO[sd][r] / ls[r]);
    }
}

// ---------------- launch ----------------
extern "C" void kernel_launch(void* const* d_in, const int* in_sizes, int n_in,
                              void* d_out, int out_size, void* d_ws,
                              size_t ws_size, hipStream_t stream) {
  const float* x = (const float*)d_in[0];
  const float* Wq = (const float*)d_in[1];
  const float* Wk = (const float*)d_in[2];
  const float* Wv = (const float*)d_in[3];
  const float* Wo = (const float*)d_in[4];
  const float* bo = (const float*)d_in[5];

  char* ws = (char*)d_ws;
  unsigned short* xb = (unsigned short*)(ws);                        // 16 MB
  unsigned short* Wqkv = (unsigned short*)(ws + (size_t)(16 << 20)); // 6 MB
  unsigned short* Wob = (unsigned short*)(ws + (size_t)(22 << 20));  // 2 MB
  unsigned short* QKV = (unsigned short*)(ws + (size_t)(24 << 20));  // 48 MB
  unsigned short* AO = (unsigned short*)(ws + (size_t)(72 << 20));   // 16 MB

  const int M = 8192, D = 1024;
  const float QSCALE = 0.125f * 1.44269504088896340736f;  // 1/sqrt(dk)*log2(e)

  cvt_f32_bf16<<<M * D / 2048, 256, 0, stream>>>(x, xb, M * D, 1.0f);
  cvt_f32_bf16<<<D * D / 2048, 256, 0, stream>>>(Wq, Wqkv, D * D, QSCALE);
  cvt_f32_bf16<<<D * D / 2048, 256, 0, stream>>>(Wk, Wqkv + D * D, D * D, 1.0f);
  cvt_f32_bf16<<<D * D / 2048, 256, 0, stream>>>(Wv, Wqkv + 2 * D * D, D * D, 1.0f);
  cvt_f32_bf16<<<D * D / 2048, 256, 0, stream>>>(Wo, Wob, D * D, 1.0f);

  // QKV projection: M=8192, N=3072 -> grid 32*12 = 384 (div by 8)
  gemm_nt2<256, 0><<<(M / 256) * (3072 / 256), 512, 0, stream>>>(
      xb, Wqkv, QKV, nullptr, M, 3072, D, 3072 / 256);

  dim3 g2(32, 64);
  attn_fwd<<<g2, 256, 0, stream>>>(QKV, AO);

  // O projection: M=8192, N=1024, BN=128 -> grid 32*8 = 256 (div by 8)
  gemm_nt2<128, 1><<<(M / 256) * (D / 128), 512, 0, stream>>>(
      AO, Wob, d_out, bo, M, D, D, D / 128);
}

// Round 7
// 329.238 us; speedup vs baseline: 1.0990x; 1.0990x over previous
//
#include <hip/hip_runtime.h>

typedef __attribute__((ext_vector_type(8))) short short8;
typedef __attribute__((ext_vector_type(4))) float f32x4;

#define GLOAD16(gp, lp)                                                        \
  __builtin_amdgcn_global_load_lds(                                            \
      (const __attribute__((address_space(1))) void*)(gp),                     \
      (__attribute__((address_space(3))) void*)(lp), 16, 0, 0)

__device__ __forceinline__ unsigned short f2bf(float f) {
  unsigned int u = __builtin_bit_cast(unsigned int, f);
  u += 0x7fffu + ((u >> 16) & 1u);
  return (unsigned short)(u >> 16);
}

// ---------------- f32 -> bf16 converts ----------------
__global__ __launch_bounds__(256) void cvt_f32_bf16(
    const float* __restrict__ src, unsigned short* __restrict__ dst, int n,
    float scale) {
  int i = (blockIdx.x * 256 + threadIdx.x) * 8;
  if (i + 8 <= n) {
    float4 a = *(const float4*)(src + i);
    float4 b = *(const float4*)(src + i + 4);
    short8 r;
    r[0] = (short)f2bf(a.x * scale); r[1] = (short)f2bf(a.y * scale);
    r[2] = (short)f2bf(a.z * scale); r[3] = (short)f2bf(a.w * scale);
    r[4] = (short)f2bf(b.x * scale); r[5] = (short)f2bf(b.y * scale);
    r[6] = (short)f2bf(b.z * scale); r[7] = (short)f2bf(b.w * scale);
    *(short8*)(dst + i) = r;
  }
}

// all 4 weight matrices in one launch (blockIdx.y selects source)
__global__ __launch_bounds__(256) void cvt_w4(
    const float* __restrict__ Wq, const float* __restrict__ Wk,
    const float* __restrict__ Wv, const float* __restrict__ Wo,
    unsigned short* __restrict__ Wqkv, unsigned short* __restrict__ Wob,
    int DD, float qscale) {
  const int y = blockIdx.y;
  const float* src = (y == 0) ? Wq : (y == 1) ? Wk : (y == 2) ? Wv : Wo;
  unsigned short* dst = (y < 3) ? Wqkv + (size_t)y * DD : Wob;
  const float scale = (y == 0) ? qscale : 1.0f;
  int i = (blockIdx.x * 256 + threadIdx.x) * 8;
  if (i + 8 <= DD) {
    float4 a = *(const float4*)(src + i);
    float4 b = *(const float4*)(src + i + 4);
    short8 r;
    r[0] = (short)f2bf(a.x * scale); r[1] = (short)f2bf(a.y * scale);
    r[2] = (short)f2bf(a.z * scale); r[3] = (short)f2bf(a.w * scale);
    r[4] = (short)f2bf(b.x * scale); r[5] = (short)f2bf(b.y * scale);
    r[6] = (short)f2bf(b.z * scale); r[7] = (short)f2bf(b.w * scale);
    *(short8*)(dst + i) = r;
  }
}

// ---------------- NT GEMM 256xBN, 2-phase double-buffered ----------------
// 512 threads = 8 waves (2M x BN/WNSZ). Grid sized for EXACT blocks/CU
// residency (R6 lesson: 384 blocks @1/CU cap = 1.5 rounds = 75% util).
template <int BN, int OUTF32>
__global__ __launch_bounds__(512) void gemm_nt2(
    const unsigned short* __restrict__ A, const unsigned short* __restrict__ B,
    void* __restrict__ Cout, const float* __restrict__ bias, int M, int N,
    int K, int nwg_y) {
  constexpr int NF = BN / 64;
  constexpr int WNSZ = BN / 4;
  __shared__ __align__(16) unsigned short As[2][256][64];
  __shared__ __align__(16) unsigned short Bs[2][BN][64];

  const int nwg = gridDim.x;
  const int id = blockIdx.x;
  const int sw = (id & 7) * (nwg >> 3) + (id >> 3);
  const int bx = sw / nwg_y, by = sw % nwg_y;
  const int row0 = bx * 256, col0 = by * BN;

  const int tid = threadIdx.x;
  const int wave = tid >> 6, lane = tid & 63;
  const int wm = wave >> 2, wn = wave & 3;
  const int l15 = lane & 15, l16 = lane >> 4;
  const int lrow = lane >> 3, lcol = (lane & 7) * 8;
  const int wv8 = wave * 8;

  f32x4 acc[8][NF];
#pragma unroll
  for (int m = 0; m < 8; ++m)
#pragma unroll
    for (int n = 0; n < NF; ++n) acc[m][n] = f32x4{0.f, 0.f, 0.f, 0.f};

  const int nt = K >> 6;

#define STAGE_TILE(buf, k0)                                                    \
  {                                                                            \
    _Pragma("unroll") for (int j = 0; j < 4; ++j) {                            \
      const unsigned short* gp =                                               \
          A + (size_t)(row0 + j * 64 + wv8 + lrow) * K + (k0) + lcol;          \
      GLOAD16(gp, &As[buf][j * 64 + wv8][0]);                                  \
    }                                                                          \
    _Pragma("unroll") for (int j = 0; j < NF; ++j) {                           \
      const unsigned short* gp =                                               \
          B + (size_t)(col0 + j * 64 + wv8 + lrow) * K + (k0) + lcol;          \
      GLOAD16(gp, &Bs[buf][j * 64 + wv8][0]);                                  \
    }                                                                          \
  }

  STAGE_TILE(0, 0)
  __syncthreads();

  for (int t = 0; t < nt; ++t) {
    const int cur = t & 1;
    if (t + 1 < nt) STAGE_TILE(cur ^ 1, (t + 1) << 6)

#pragma unroll
    for (int kk = 0; kk < 2; ++kk) {
      short8 a[8], b[NF];
#pragma unroll
      for (int m = 0; m < 8; ++m)
        a[m] = *(const short8*)&As[cur][wm * 128 + m * 16 + l15][kk * 32 + l16 * 8];
#pragma unroll
      for (int n = 0; n < NF; ++n)
        b[n] = *(const short8*)&Bs[cur][wn * WNSZ + n * 16 + l15][kk * 32 + l16 * 8];
#pragma unroll
      for (int m = 0; m < 8; ++m)
#pragma unroll
        for (int n = 0; n < NF; ++n)
          acc[m][n] =
              __builtin_amdgcn_mfma_f32_16x16x32_bf16(a[m], b[n], acc[m][n], 0, 0, 0);
    }
    __syncthreads();
  }

#pragma unroll
  for (int m = 0; m < 8; ++m) {
    const int row = row0 + wm * 128 + m * 16 + l16 * 4;
#pragma unroll
    for (int n = 0; n < NF; ++n) {
      const int col = col0 + wn * WNSZ + n * 16 + l15;
      float bv = 0.f;
      if (OUTF32) bv = bias[col];
#pragma unroll
      for (int r = 0; r < 4; ++r) {
        const float v = acc[m][n][r] + bv;
        if (OUTF32)
          ((float*)Cout)[(size_t)(row + r) * N + col] = v;
        else
          ((unsigned short*)Cout)[(size_t)(row + r) * N + col] = f2bf(v);
      }
    }
  }
#undef STAGE_TILE
}

// ---------------- causal flash attention: QBLK=128, 8 waves ----------------
// Per-wave inner loop identical to R4-verified code. Waves 0-3 stage V
// (reg->swizzled LDS), waves 4-7 stage K (gload_lds, pre-swizzled source).
// K/VT shared by 8 waves -> LDS 48KB -> 3 blocks/CU (24 waves/CU cap).
__global__ __launch_bounds__(512) void attn_fwd(
    const unsigned short* __restrict__ QKV, unsigned short* __restrict__ AO) {
  const int S = 2048, LD = 3072;
  const int qt = gridDim.x - 1 - blockIdx.x;  // long blocks first
  const int bh = blockIdx.y, b = bh >> 4, h = bh & 15;
  const int tid = threadIdx.x, wave = tid >> 6, lane = tid & 63;
  const int l15 = lane & 15, l16 = lane >> 4;
  const int q0 = qt * 128;

  __shared__ __align__(16) char KsB[2][64 * 128];
  __shared__ __align__(16) char VTB[2][64 * 128];
  __shared__ __align__(16) char PlB[8][16 * 128];

  const unsigned short* qptr =
      QKV + (size_t)(b * S + q0 + wave * 16 + l15) * LD + h * 64 + l16 * 8;
  short8 qf[2];
  qf[0] = *(const short8*)(qptr);
  qf[1] = *(const short8*)(qptr + 32);

  const int krow = lane >> 3;
  const int kcol = (((lane & 7) ^ (lane >> 3)) & 7) * 8;
  const int vp_ = tid & 31, vd0 = ((tid >> 5) & 7) * 8;  // waves 0-3 only

  float mrow = -1e30f, lsum = 0.f;
  f32x4 accO[4] = {};
  const int nkv = 2 * qt + 2;

  // ---- prologue: stage tile 0 into buffer 0
  {
    if (wave >= 4) {
#pragma unroll
      for (int i = 0; i < 2; ++i) {
        const int c = (wave - 4) * 2 + i;
        const unsigned short* gp =
            QKV + (size_t)(b * S + c * 8 + krow) * LD + 1024 + h * 64 + kcol;
        GLOAD16(gp, KsB[0] + c * 1024);
      }
    } else {
      const unsigned short* vp =
          QKV + (size_t)(b * S + 2 * vp_) * LD + 2048 + h * 64 + vd0;
      short8 va = *(const short8*)vp;
      short8 vb = *(const short8*)(vp + LD);
      uint4 vaw = __builtin_bit_cast(uint4, va);
      uint4 vbw = __builtin_bit_cast(uint4, vb);
      const unsigned int aw[4] = {vaw.x, vaw.y, vaw.z, vaw.w};
      const unsigned int bw[4] = {vbw.x, vbw.y, vbw.z, vbw.w};
#pragma unroll
      for (int w = 0; w < 4; ++w) {
        unsigned int e = __builtin_amdgcn_perm(bw[w], aw[w], 0x05040100u);
        unsigned int o = __builtin_amdgcn_perm(bw[w], aw[w], 0x07060302u);
        *(unsigned int*)(VTB[0] + (((vd0 + 2 * w) * 128 + 4 * vp_) ^ ((2 * w) << 4))) = e;
        *(unsigned int*)(VTB[0] + (((vd0 + 2 * w + 1) * 128 + 4 * vp_) ^ ((2 * w + 1) << 4))) = o;
      }
    }
  }
  __syncthreads();

  for (int t = 0; t < nkv; ++t) {
    const int cur = t & 1, kv0 = t * 64;

    // --- swapped QK^T
    f32x4 accS[4] = {};
#pragma unroll
    for (int sub = 0; sub < 4; ++sub) {
      const int rw = sub * 16 + l15;
#pragma unroll
      for (int kk = 0; kk < 2; ++kk) {
        short8 kf = *(const short8*)(KsB[cur] + rw * 128 +
                                     ((kk * 64 + l16 * 16) ^ ((l15 & 7) << 4)));
        accS[sub] =
            __builtin_amdgcn_mfma_f32_16x16x32_bf16(kf, qf[kk], accS[sub], 0, 0, 0);
      }
    }

    // --- prefetch next tile (waves 4-7: K gload; waves 0-3: V reg load)
    short8 va, vb;
    const bool pre = (t + 1 < nkv);
    if (pre) {
      const int kvn = kv0 + 64;
      if (wave >= 4) {
#pragma unroll
        for (int i = 0; i < 2; ++i) {
          const int c = (wave - 4) * 2 + i;
          const unsigned short* gp =
              QKV + (size_t)(b * S + kvn + c * 8 + krow) * LD + 1024 + h * 64 + kcol;
          GLOAD16(gp, KsB[cur ^ 1] + c * 1024);
        }
      } else {
        const unsigned short* vp =
            QKV + (size_t)(b * S + kvn + 2 * vp_) * LD + 2048 + h * 64 + vd0;
        va = *(const short8*)vp;
        vb = *(const short8*)(vp + LD);
      }
    }

    // --- mask (diagonal tiles only; wave-uniform branch) + row max
    const bool nm = (kv0 + 63 > q0 + wave * 16);
    float mx = -1e30f;
    if (nm) {
      const int qabs = q0 + wave * 16 + l15;
#pragma unroll
      for (int sub = 0; sub < 4; ++sub)
#pragma unroll
        for (int r = 0; r < 4; ++r) {
          float s = accS[sub][r];
          if (kv0 + sub * 16 + l16 * 4 + r > qabs) s = -1e30f;
          accS[sub][r] = s;
          mx = fmaxf(mx, s);
        }
    } else {
#pragma unroll
      for (int sub = 0; sub < 4; ++sub)
#pragma unroll
        for (int r = 0; r < 4; ++r) mx = fmaxf(mx, accS[sub][r]);
    }
    mx = fmaxf(mx, __shfl_xor(mx, 16));
    mx = fmaxf(mx, __shfl_xor(mx, 32));

    // --- defer-max (T13)
    if (__any(mx > mrow + 8.0f)) {
      const float mnew = fmaxf(mrow, mx);
      const float alpha = exp2f(mrow - mnew);
      mrow = mnew;
      lsum *= alpha;
      float al[4];
#pragma unroll
      for (int r = 0; r < 4; ++r) al[r] = __shfl(alpha, l16 * 4 + r);
#pragma unroll
      for (int sd = 0; sd < 4; ++sd)
#pragma unroll
        for (int r = 0; r < 4; ++r) accO[sd][r] *= al[r];
    }

    // --- P = exp2(S - mrow), pack, sum
    float rs = 0.f;
#pragma unroll
    for (int sub = 0; sub < 4; ++sub) {
      float p0 = exp2f(accS[sub][0] - mrow);
      float p1 = exp2f(accS[sub][1] - mrow);
      float p2 = exp2f(accS[sub][2] - mrow);
      float p3 = exp2f(accS[sub][3] - mrow);
      rs += (p0 + p1) + (p2 + p3);
      unsigned int pk01, pk23;
      asm("v_cvt_pk_bf16_f32 %0, %1, %2" : "=v"(pk01) : "v"(p0), "v"(p1));
      asm("v_cvt_pk_bf16_f32 %0, %1, %2" : "=v"(pk23) : "v"(p2), "v"(p3));
      uint2 pw = {pk01, pk23};
      *(uint2*)(PlB[wave] +
                ((l15 * 128 + sub * 32 + l16 * 8) ^ ((l15 & 7) << 4))) = pw;
    }
    rs += __shfl_xor(rs, 16);
    rs += __shfl_xor(rs, 32);
    lsum += rs;

    // --- write next V^T (waves 0-3)
    if (pre && wave < 4) {
      uint4 vaw = __builtin_bit_cast(uint4, va);
      uint4 vbw = __builtin_bit_cast(uint4, vb);
      const unsigned int aw[4] = {vaw.x, vaw.y, vaw.z, vaw.w};
      const unsigned int bw[4] = {vbw.x, vbw.y, vbw.z, vbw.w};
#pragma unroll
      for (int w = 0; w < 4; ++w) {
        unsigned int e = __builtin_amdgcn_perm(bw[w], aw[w], 0x05040100u);
        unsigned int o = __builtin_amdgcn_perm(bw[w], aw[w], 0x07060302u);
        *(unsigned int*)(VTB[cur ^ 1] +
                         (((vd0 + 2 * w) * 128 + 4 * vp_) ^ ((2 * w) << 4))) = e;
        *(unsigned int*)(VTB[cur ^ 1] +
                         (((vd0 + 2 * w + 1) * 128 + 4 * vp_) ^ ((2 * w + 1) << 4))) = o;
      }
    }

    // --- PV
#pragma unroll
    for (int kk = 0; kk < 2; ++kk) {
      short8 pf = *(const short8*)(PlB[wave] + ((l15 * 128 + kk * 64 + l16 * 16) ^
                                               ((l15 & 7) << 4)));
#pragma unroll
      for (int sd = 0; sd < 4; ++sd) {
        short8 vf = *(const short8*)(VTB[cur] + (sd * 16 + l15) * 128 +
                                     ((kk * 64 + l16 * 16) ^ ((l15 & 7) << 4)));
        accO[sd] =
            __builtin_amdgcn_mfma_f32_16x16x32_bf16(pf, vf, accO[sd], 0, 0, 0);
      }
    }
    __syncthreads();
  }

  // --- epilogue
  float ls[4];
#pragma unroll
  for (int r = 0; r < 4; ++r) ls[r] = __shfl(lsum, l16 * 4 + r);
#pragma unroll
  for (int sd = 0; sd < 4; ++sd)
#pragma unroll
    for (int r = 0; r < 4; ++r) {
      AO[(size_t)(b * S + q0 + wave * 16 + l16 * 4 + r) * 1024 + h * 64 +
         sd * 16 + l15] = f2bf(accO[sd][r] / ls[r]);
    }
}

// ---------------- launch ----------------
extern "C" void kernel_launch(void* const* d_in, const int* in_sizes, int n_in,
                              void* d_out, int out_size, void* d_ws,
                              size_t ws_size, hipStream_t stream) {
  const float* x = (const float*)d_in[0];
  const float* Wq = (const float*)d_in[1];
  const float* Wk = (const float*)d_in[2];
  const float* Wv = (const float*)d_in[3];
  const float* Wo = (const float*)d_in[4];
  const float* bo = (const float*)d_in[5];

  char* ws = (char*)d_ws;
  unsigned short* xb = (unsigned short*)(ws);                        // 16 MB
  unsigned short* Wqkv = (unsigned short*)(ws + (size_t)(16 << 20)); // 6 MB
  unsigned short* Wob = (unsigned short*)(ws + (size_t)(22 << 20));  // 2 MB
  unsigned short* QKV = (unsigned short*)(ws + (size_t)(24 << 20));  // 48 MB
  unsigned short* AO = (unsigned short*)(ws + (size_t)(72 << 20));   // 16 MB

  const int M = 8192, D = 1024;
  const float QSCALE = 0.125f * 1.44269504088896340736f;  // 1/sqrt(dk)*log2(e)

  cvt_f32_bf16<<<M * D / 2048, 256, 0, stream>>>(x, xb, M * D, 1.0f);
  dim3 gw(D * D / 2048, 4);
  cvt_w4<<<gw, 256, 0, stream>>>(Wq, Wk, Wv, Wo, Wqkv, Wob, D * D, QSCALE);

  // QKV projection: BN=192 -> grid 32*16 = 512 (2.0 blocks/CU exact, %8==0)
  gemm_nt2<192, 0><<<(M / 256) * (3072 / 192), 512, 0, stream>>>(
      xb, Wqkv, QKV, nullptr, M, 3072, D, 3072 / 192);

  // attention: QBLK=128 -> grid (16, 64), 512 threads
  dim3 g2(16, 64);
  attn_fwd<<<g2, 512, 0, stream>>>(QKV, AO);

  // O projection: BN=128 -> grid 32*8 = 256 (1.0 blocks/CU exact)
  gemm_nt2<128, 1><<<(M / 256) * (D / 128), 512, 0, stream>>>(
      AO, Wob, d_out, bo, M, D, D, D / 128);
}

// Round 11
// 322.256 us; speedup vs baseline: 1.1228x; 1.0217x over previous
//
#include <hip/hip_runtime.h>

typedef __attribute__((ext_vector_type(8))) short short8;
typedef __attribute__((ext_vector_type(4))) float f32x4;

#define GLOAD16(gp, lp)                                                        \
  __builtin_amdgcn_global_load_lds(                                            \
      (const __attribute__((address_space(1))) void*)(gp),                     \
      (__attribute__((address_space(3))) void*)(lp), 16, 0, 0)

__device__ __forceinline__ unsigned short f2bf(float f) {
  unsigned int u = __builtin_bit_cast(unsigned int, f);
  u += 0x7fffu + ((u >> 16) & 1u);
  return (unsigned short)(u >> 16);
}

// ---------------- f32 -> bf16 converts ----------------
__global__ __launch_bounds__(256) void cvt_f32_bf16(
    const float* __restrict__ src, unsigned short* __restrict__ dst, int n,
    float scale) {
  int i = (blockIdx.x * 256 + threadIdx.x) * 8;
  if (i + 8 <= n) {
    float4 a = *(const float4*)(src + i);
    float4 b = *(const float4*)(src + i + 4);
    short8 r;
    r[0] = (short)f2bf(a.x * scale); r[1] = (short)f2bf(a.y * scale);
    r[2] = (short)f2bf(a.z * scale); r[3] = (short)f2bf(a.w * scale);
    r[4] = (short)f2bf(b.x * scale); r[5] = (short)f2bf(b.y * scale);
    r[6] = (short)f2bf(b.z * scale); r[7] = (short)f2bf(b.w * scale);
    *(short8*)(dst + i) = r;
  }
}

__global__ __launch_bounds__(256) void cvt_w4(
    const float* __restrict__ Wq, const float* __restrict__ Wk,
    const float* __restrict__ Wv, const float* __restrict__ Wo,
    unsigned short* __restrict__ Wqkv, unsigned short* __restrict__ Wob,
    int DD, float qscale) {
  const int y = blockIdx.y;
  const float* src = (y == 0) ? Wq : (y == 1) ? Wk : (y == 2) ? Wv : Wo;
  unsigned short* dst = (y < 3) ? Wqkv + (size_t)y * DD : Wob;
  const float scale = (y == 0) ? qscale : 1.0f;
  int i = (blockIdx.x * 256 + threadIdx.x) * 8;
  if (i + 8 <= DD) {
    float4 a = *(const float4*)(src + i);
    float4 b = *(const float4*)(src + i + 4);
    short8 r;
    r[0] = (short)f2bf(a.x * scale); r[1] = (short)f2bf(a.y * scale);
    r[2] = (short)f2bf(a.z * scale); r[3] = (short)f2bf(a.w * scale);
    r[4] = (short)f2bf(b.x * scale); r[5] = (short)f2bf(b.y * scale);
    r[6] = (short)f2bf(b.z * scale); r[7] = (short)f2bf(b.w * scale);
    *(short8*)(dst + i) = r;
  }
}

// ---------------- NT GEMM 256xBN, 2-phase (frozen from R7) ----------------
template <int BN, int OUTF32>
__global__ __launch_bounds__(512) void gemm_nt2(
    const unsigned short* __restrict__ A, const unsigned short* __restrict__ B,
    void* __restrict__ Cout, const float* __restrict__ bias, int M, int N,
    int K, int nwg_y) {
  constexpr int NF = BN / 64;
  constexpr int WNSZ = BN / 4;
  __shared__ __align__(16) unsigned short As[2][256][64];
  __shared__ __align__(16) unsigned short Bs[2][BN][64];

  const int nwg = gridDim.x;
  const int id = blockIdx.x;
  const int sw = (id & 7) * (nwg >> 3) + (id >> 3);
  const int bx = sw / nwg_y, by = sw % nwg_y;
  const int row0 = bx * 256, col0 = by * BN;

  const int tid = threadIdx.x;
  const int wave = tid >> 6, lane = tid & 63;
  const int wm = wave >> 2, wn = wave & 3;
  const int l15 = lane & 15, l16 = lane >> 4;
  const int lrow = lane >> 3, lcol = (lane & 7) * 8;
  const int wv8 = wave * 8;

  f32x4 acc[8][NF];
#pragma unroll
  for (int m = 0; m < 8; ++m)
#pragma unroll
    for (int n = 0; n < NF; ++n) acc[m][n] = f32x4{0.f, 0.f, 0.f, 0.f};

  const int nt = K >> 6;

#define STAGE_TILE(buf, k0)                                                    \
  {                                                                            \
    _Pragma("unroll") for (int j = 0; j < 4; ++j) {                            \
      const unsigned short* gp =                                               \
          A + (size_t)(row0 + j * 64 + wv8 + lrow) * K + (k0) + lcol;          \
      GLOAD16(gp, &As[buf][j * 64 + wv8][0]);                                  \
    }                                                                          \
    _Pragma("unroll") for (int j = 0; j < NF; ++j) {                           \
      const unsigned short* gp =                                               \
          B + (size_t)(col0 + j * 64 + wv8 + lrow) * K + (k0) + lcol;          \
      GLOAD16(gp, &Bs[buf][j * 64 + wv8][0]);                                  \
    }                                                                          \
  }

  STAGE_TILE(0, 0)
  __syncthreads();

  for (int t = 0; t < nt; ++t) {
    const int cur = t & 1;
    if (t + 1 < nt) STAGE_TILE(cur ^ 1, (t + 1) << 6)

#pragma unroll
    for (int kk = 0; kk < 2; ++kk) {
      short8 a[8], b[NF];
#pragma unroll
      for (int m = 0; m < 8; ++m)
        a[m] = *(const short8*)&As[cur][wm * 128 + m * 16 + l15][kk * 32 + l16 * 8];
#pragma unroll
      for (int n = 0; n < NF; ++n)
        b[n] = *(const short8*)&Bs[cur][wn * WNSZ + n * 16 + l15][kk * 32 + l16 * 8];
#pragma unroll
      for (int m = 0; m < 8; ++m)
#pragma unroll
        for (int n = 0; n < NF; ++n)
          acc[m][n] =
              __builtin_amdgcn_mfma_f32_16x16x32_bf16(a[m], b[n], acc[m][n], 0, 0, 0);
    }
    __syncthreads();
  }

#pragma unroll
  for (int m = 0; m < 8; ++m) {
    const int row = row0 + wm * 128 + m * 16 + l16 * 4;
#pragma unroll
    for (int n = 0; n < NF; ++n) {
      const int col = col0 + wn * WNSZ + n * 16 + l15;
      float bv = 0.f;
      if (OUTF32) bv = bias[col];
#pragma unroll
      for (int r = 0; r < 4; ++r) {
        const float v = acc[m][n][r] + bv;
        if (OUTF32)
          ((float*)Cout)[(size_t)(row + r) * N + col] = v;
        else
          ((unsigned short*)Cout)[(size_t)(row + r) * N + col] = f2bf(v);
      }
    }
  }
#undef STAGE_TILE
}

// ---------------- causal flash attention: in-register P ----------------
// K rows staged PERMUTED (kvperm) so QK^T's C-layout accS is EXACTLY the
// PV B-operand fragment after cvt_pk (no P LDS round-trip, no shuffles).
// PV swapped (A=V^T frag) -> accO = O^T; alpha/lsum are pure per-lane
// scalars (q = l15 for every value a lane holds). LDS 32KB -> 4 blocks/CU.
__device__ __forceinline__ int kvperm(int slot) {
  const int s = slot >> 4, l = (slot >> 2) & 3, rr = slot & 3;
  return 32 * (s & 1) + 8 * l + 4 * (s >> 1) + rr;
}

__global__ __launch_bounds__(512) void attn_fwd(
    const unsigned short* __restrict__ QKV, unsigned short* __restrict__ AO) {
  const int S = 2048, LD = 3072;
  const int qt = gridDim.x - 1 - blockIdx.x;  // long blocks first
  const int bh = blockIdx.y, b = bh >> 4, h = bh & 15;
  const int tid = threadIdx.x, wave = tid >> 6, lane = tid & 63;
  const int l15 = lane & 15, l16 = lane >> 4;
  const int q0 = qt * 128;

  __shared__ __align__(16) char KsB[2][64 * 128];
  __shared__ __align__(16) char VTB[2][64 * 128];

  const unsigned short* qptr =
      QKV + (size_t)(b * S + q0 + wave * 16 + l15) * LD + h * 64 + l16 * 8;
  short8 qf[2];
  qf[0] = *(const short8*)(qptr);
  qf[1] = *(const short8*)(qptr + 32);

  const int krow = lane >> 3;
  const int kcol = (((lane & 7) ^ (lane >> 3)) & 7) * 8;
  // waves 4-7 stage K chunks c = (wave-4)*2 + i; permuted source rows:
  int kvp[2];
#pragma unroll
  for (int i = 0; i < 2; ++i)
    kvp[i] = kvperm(((wave - 4) * 2 + i) * 8 + krow);
  const int vp_ = tid & 31, vd0 = ((tid >> 5) & 7) * 8;  // waves 0-3

  float mrow = -1e30f, lsum = 0.f;
  f32x4 accO[4] = {};
  const int nkv = 2 * qt + 2;
  // kv offset of accS[sub][r]: kv0 + 32*(sub&1) + 4*(sub>>1) + 8*l16 + r
  const int koff8 = 8 * l16;

  // ---- prologue: stage tile 0
  {
    if (wave >= 4) {
#pragma unroll
      for (int i = 0; i < 2; ++i) {
        const int c = (wave - 4) * 2 + i;
        const unsigned short* gp =
            QKV + (size_t)(b * S + kvp[i]) * LD + 1024 + h * 64 + kcol;
        GLOAD16(gp, KsB[0] + c * 1024);
      }
    } else {
      const unsigned short* vp =
          QKV + (size_t)(b * S + 2 * vp_) * LD + 2048 + h * 64 + vd0;
      short8 va = *(const short8*)vp;
      short8 vb = *(const short8*)(vp + LD);
      uint4 vaw = __builtin_bit_cast(uint4, va);
      uint4 vbw = __builtin_bit_cast(uint4, vb);
      const unsigned int aw[4] = {vaw.x, vaw.y, vaw.z, vaw.w};
      const unsigned int bw[4] = {vbw.x, vbw.y, vbw.z, vbw.w};
#pragma unroll
      for (int w = 0; w < 4; ++w) {
        unsigned int e = __builtin_amdgcn_perm(bw[w], aw[w], 0x05040100u);
        unsigned int o = __builtin_amdgcn_perm(bw[w], aw[w], 0x07060302u);
        *(unsigned int*)(VTB[0] + (((vd0 + 2 * w) * 128 + 4 * vp_) ^ ((2 * w) << 4))) = e;
        *(unsigned int*)(VTB[0] + (((vd0 + 2 * w + 1) * 128 + 4 * vp_) ^ ((2 * w + 1) << 4))) = o;
      }
    }
  }
  __syncthreads();

  for (int t = 0; t < nkv; ++t) {
    const int cur = t & 1, kv0 = t * 64;

    // --- swapped QK^T; rows permuted so accS == PV B-fragment layout
    f32x4 accS[4] = {};
#pragma unroll
    for (int sub = 0; sub < 4; ++sub) {
      const int rw = sub * 16 + l15;
#pragma unroll
      for (int kk = 0; kk < 2; ++kk) {
        short8 kf = *(const short8*)(KsB[cur] + rw * 128 +
                                     ((kk * 64 + l16 * 16) ^ ((l15 & 7) << 4)));
        accS[sub] =
            __builtin_amdgcn_mfma_f32_16x16x32_bf16(kf, qf[kk], accS[sub], 0, 0, 0);
      }
    }

    // --- prefetch next tile
    short8 va, vb;
    const bool pre = (t + 1 < nkv);
    if (pre) {
      const int kvn = kv0 + 64;
      if (wave >= 4) {
#pragma unroll
        for (int i = 0; i < 2; ++i) {
          const int c = (wave - 4) * 2 + i;
          const unsigned short* gp =
              QKV + (size_t)(b * S + kvn + kvp[i]) * LD + 1024 + h * 64 + kcol;
          GLOAD16(gp, KsB[cur ^ 1] + c * 1024);
        }
      } else {
        const unsigned short* vp =
            QKV + (size_t)(b * S + kvn + 2 * vp_) * LD + 2048 + h * 64 + vd0;
        va = *(const short8*)vp;
        vb = *(const short8*)(vp + LD);
      }
    }

    // --- mask (diagonal tiles only) + row max. kv of accS[sub][r]:
    //     kv0 + 32*(sub&1) + 4*(sub>>1) + 8*l16 + r
    const bool nm = (kv0 + 63 > q0 + wave * 16);
    float mx = -1e30f;
    if (nm) {
      const int qabs = q0 + wave * 16 + l15;
#pragma unroll
      for (int sub = 0; sub < 4; ++sub) {
        const int kbase = kv0 + 32 * (sub & 1) + 4 * (sub >> 1) + koff8;
#pragma unroll
        for (int r = 0; r < 4; ++r) {
          float s = accS[sub][r];
          if (kbase + r > qabs) s = -1e30f;
          accS[sub][r] = s;
          mx = fmaxf(mx, s);
        }
      }
    } else {
#pragma unroll
      for (int sub = 0; sub < 4; ++sub)
#pragma unroll
        for (int r = 0; r < 4; ++r) mx = fmaxf(mx, accS[sub][r]);
    }
    mx = fmaxf(mx, __shfl_xor(mx, 16));
    mx = fmaxf(mx, __shfl_xor(mx, 32));

    // --- defer-max (T13); alpha is a pure per-lane scalar now
    if (__any(mx > mrow + 8.0f)) {
      const float mnew = fmaxf(mrow, mx);
      const float alpha = exp2f(mrow - mnew);
      mrow = mnew;
      lsum *= alpha;
#pragma unroll
      for (int sd = 0; sd < 4; ++sd)
#pragma unroll
        for (int r = 0; r < 4; ++r) accO[sd][r] *= alpha;
    }

    // --- P = exp2(S - mrow); pack straight into PV B-fragments
    float rs = 0.f;
#pragma unroll
    for (int sub = 0; sub < 4; ++sub)
#pragma unroll
      for (int r = 0; r < 4; ++r) {
        const float pv = exp2f(accS[sub][r] - mrow);
        accS[sub][r] = pv;
        rs += pv;
      }
    rs += __shfl_xor(rs, 16);
    rs += __shfl_xor(rs, 32);
    lsum += rs;

    short8 pf[2];
#pragma unroll
    for (int kk = 0; kk < 2; ++kk) {
      unsigned int w0, w1, w2, w3;
      asm("v_cvt_pk_bf16_f32 %0, %1, %2" : "=v"(w0) : "v"(accS[kk][0]), "v"(accS[kk][1]));
      asm("v_cvt_pk_bf16_f32 %0, %1, %2" : "=v"(w1) : "v"(accS[kk][2]), "v"(accS[kk][3]));
      asm("v_cvt_pk_bf16_f32 %0, %1, %2" : "=v"(w2) : "v"(accS[kk + 2][0]), "v"(accS[kk + 2][1]));
      asm("v_cvt_pk_bf16_f32 %0, %1, %2" : "=v"(w3) : "v"(accS[kk + 2][2]), "v"(accS[kk + 2][3]));
      uint4 u = {w0, w1, w2, w3};
      pf[kk] = __builtin_bit_cast(short8, u);
    }

    // --- write next V^T (waves 0-3)
    if (pre && wave < 4) {
      uint4 vaw = __builtin_bit_cast(uint4, va);
      uint4 vbw = __builtin_bit_cast(uint4, vb);
      const unsigned int aw[4] = {vaw.x, vaw.y, vaw.z, vaw.w};
      const unsigned int bw[4] = {vbw.x, vbw.y, vbw.z, vbw.w};
#pragma unroll
      for (int w = 0; w < 4; ++w) {
        unsigned int e = __builtin_amdgcn_perm(bw[w], aw[w], 0x05040100u);
        unsigned int o = __builtin_amdgcn_perm(bw[w], aw[w], 0x07060302u);
        *(unsigned int*)(VTB[cur ^ 1] +
                         (((vd0 + 2 * w) * 128 + 4 * vp_) ^ ((2 * w) << 4))) = e;
        *(unsigned int*)(VTB[cur ^ 1] +
                         (((vd0 + 2 * w + 1) * 128 + 4 * vp_) ^ ((2 * w + 1) << 4))) = o;
      }
    }

    // --- PV swapped: accO[sd] = O^T quadrant (rows d, cols q)
#pragma unroll
    for (int kk = 0; kk < 2; ++kk) {
#pragma unroll
      for (int sd = 0; sd < 4; ++sd) {
        short8 vf = *(const short8*)(VTB[cur] + (sd * 16 + l15) * 128 +
                                     ((kk * 64 + l16 * 16) ^ ((l15 & 7) << 4)));
        accO[sd] =
            __builtin_amdgcn_mfma_f32_16x16x32_bf16(vf, pf[kk], accO[sd], 0, 0, 0);
      }
    }
    __syncthreads();
  }

  // --- epilogue: O[q][d] = accO^T / lsum; q = q0+wave*16+l15 (per-lane)
  const float inv = __builtin_amdgcn_rcpf(lsum);
  unsigned short* aop =
      AO + (size_t)(b * S + q0 + wave * 16 + l15) * 1024 + h * 64;
#pragma unroll
  for (int sd = 0; sd < 4; ++sd) {
    const int d = sd * 16 + l16 * 4;
    unsigned int w0, w1;
    float o0 = accO[sd][0] * inv, o1 = accO[sd][1] * inv;
    float o2 = accO[sd][2] * inv, o3 = accO[sd][3] * inv;
    asm("v_cvt_pk_bf16_f32 %0, %1, %2" : "=v"(w0) : "v"(o0), "v"(o1));
    asm("v_cvt_pk_bf16_f32 %0, %1, %2" : "=v"(w1) : "v"(o2), "v"(o3));
    *(unsigned int*)(aop + d) = w0;
    *(unsigned int*)(aop + d + 2) = w1;
  }
}

// ---------------- launch ----------------
extern "C" void kernel_launch(void* const* d_in, const int* in_sizes, int n_in,
                              void* d_out, int out_size, void* d_ws,
                              size_t ws_size, hipStream_t stream) {
  const float* x = (const float*)d_in[0];
  const float* Wq = (const float*)d_in[1];
  const float* Wk = (const float*)d_in[2];
  const float* Wv = (const float*)d_in[3];
  const float* Wo = (const float*)d_in[4];
  const float* bo = (const float*)d_in[5];

  char* ws = (char*)d_ws;
  unsigned short* xb = (unsigned short*)(ws);                        // 16 MB
  unsigned short* Wqkv = (unsigned short*)(ws + (size_t)(16 << 20)); // 6 MB
  unsigned short* Wob = (unsigned short*)(ws + (size_t)(22 << 20));  // 2 MB
  unsigned short* QKV = (unsigned short*)(ws + (size_t)(24 << 20));  // 48 MB
  unsigned short* AO = (unsigned short*)(ws + (size_t)(72 << 20));   // 16 MB

  const int M = 8192, D = 1024;
  const float QSCALE = 0.125f * 1.44269504088896340736f;  // 1/sqrt(dk)*log2(e)

  cvt_f32_bf16<<<M * D / 2048, 256, 0, stream>>>(x, xb, M * D, 1.0f);
  dim3 gw(D * D / 2048, 4);
  cvt_w4<<<gw, 256, 0, stream>>>(Wq, Wk, Wv, Wo, Wqkv, Wob, D * D, QSCALE);

  // QKV projection: BN=192 -> grid 32*16 = 512 (2.0 blocks/CU exact)
  gemm_nt2<192, 0><<<(M / 256) * (3072 / 192), 512, 0, stream>>>(
      xb, Wqkv, QKV, nullptr, M, 3072, D, 3072 / 192);

  // attention: QBLK=128 -> grid (16, 64), 512 threads
  dim3 g2(16, 64);
  attn_fwd<<<g2, 512, 0, stream>>>(QKV, AO);

  // O projection: BN=128 -> grid 32*8 = 256 (1.0 blocks/CU exact)
  gemm_nt2<128, 1><<<(M / 256) * (D / 128), 512, 0, stream>>>(
      AO, Wob, d_out, bo, M, D, D, D / 128);
}

// Round 12
// 313.813 us; speedup vs baseline: 1.1531x; 1.0269x over previous
//
#include <hip/hip_runtime.h>

typedef __attribute__((ext_vector_type(8))) short short8;
typedef __attribute__((ext_vector_type(4))) float f32x4;

#define GLOAD16(gp, lp)                                                        \
  __builtin_amdgcn_global_load_lds(                                            \
      (const __attribute__((address_space(1))) void*)(gp),                     \
      (__attribute__((address_space(3))) void*)(lp), 16, 0, 0)

__device__ __forceinline__ unsigned short f2bf(float f) {
  unsigned int u = __builtin_bit_cast(unsigned int, f);
  u += 0x7fffu + ((u >> 16) & 1u);
  return (unsigned short)(u >> 16);
}

// ---------------- f32 -> bf16 converts ----------------
__global__ __launch_bounds__(256) void cvt_f32_bf16(
    const float* __restrict__ src, unsigned short* __restrict__ dst, int n,
    float scale) {
  int i = (blockIdx.x * 256 + threadIdx.x) * 8;
  if (i + 8 <= n) {
    float4 a = *(const float4*)(src + i);
    float4 b = *(const float4*)(src + i + 4);
    short8 r;
    r[0] = (short)f2bf(a.x * scale); r[1] = (short)f2bf(a.y * scale);
    r[2] = (short)f2bf(a.z * scale); r[3] = (short)f2bf(a.w * scale);
    r[4] = (short)f2bf(b.x * scale); r[5] = (short)f2bf(b.y * scale);
    r[6] = (short)f2bf(b.z * scale); r[7] = (short)f2bf(b.w * scale);
    *(short8*)(dst + i) = r;
  }
}

__global__ __launch_bounds__(256) void cvt_w4(
    const float* __restrict__ Wq, const float* __restrict__ Wk,
    const float* __restrict__ Wv, const float* __restrict__ Wo,
    unsigned short* __restrict__ Wqkv, unsigned short* __restrict__ Wob,
    int DD, float qscale) {
  const int y = blockIdx.y;
  const float* src = (y == 0) ? Wq : (y == 1) ? Wk : (y == 2) ? Wv : Wo;
  unsigned short* dst = (y < 3) ? Wqkv + (size_t)y * DD : Wob;
  const float scale = (y == 0) ? qscale : 1.0f;
  int i = (blockIdx.x * 256 + threadIdx.x) * 8;
  if (i + 8 <= DD) {
    float4 a = *(const float4*)(src + i);
    float4 b = *(const float4*)(src + i + 4);
    short8 r;
    r[0] = (short)f2bf(a.x * scale); r[1] = (short)f2bf(a.y * scale);
    r[2] = (short)f2bf(a.z * scale); r[3] = (short)f2bf(a.w * scale);
    r[4] = (short)f2bf(b.x * scale); r[5] = (short)f2bf(b.y * scale);
    r[6] = (short)f2bf(b.z * scale); r[7] = (short)f2bf(b.w * scale);
    *(short8*)(dst + i) = r;
  }
}

// ------- NT GEMM 256x128, 3-buffer ring + counted vmcnt + T2 + T5 -------
// C[M,N] = A[M,K] * B[N,K]^T. 512 thr = 8 waves (2M x 4N), wave tile 128x32.
// While computing tile t (buf t%3): t+1 landed, t+2 in flight. Raw s_barrier
// (no drain) + per-wave s_waitcnt vmcnt(12/6/0) certifies tile t's 6 loads.
// LDS tiles XOR-swizzled via pre-swizzled gload source (rule #21 both-sides).
template <int OUTF32>
__global__ __launch_bounds__(512) void gemm_nt3(
    const unsigned short* __restrict__ A, const unsigned short* __restrict__ B,
    void* __restrict__ Cout, const float* __restrict__ bias, int M, int N,
    int K, int nwg_y) {
  __shared__ __align__(16) unsigned short As[3][256][64];   // 96 KB
  __shared__ __align__(16) unsigned short Bs[3][128][64];   // 48 KB

  const int nwg = gridDim.x;
  const int id = blockIdx.x;
  const int sw = (id & 7) * (nwg >> 3) + (id >> 3);   // nwg % 8 == 0
  const int bx = sw / nwg_y, by = sw % nwg_y;
  const int row0 = bx * 256, col0 = by * 128;

  const int tid = threadIdx.x;
  const int wave = tid >> 6, lane = tid & 63;
  const int wm = wave >> 2, wn = wave & 3;
  const int l15 = lane & 15, l16 = lane >> 4;
  const int srow = lane >> 3;                       // 0..7
  const int scol = ((lane & 7) ^ srow) * 8;         // pre-swizzled source col

  f32x4 acc[8][2];
#pragma unroll
  for (int m = 0; m < 8; ++m)
#pragma unroll
    for (int n = 0; n < 2; ++n) acc[m][n] = f32x4{0.f, 0.f, 0.f, 0.f};

  const int nt = K >> 6;  // 64-wide K tiles

#define STAGE3(buf, k0)                                                        \
  {                                                                            \
    _Pragma("unroll") for (int j = 0; j < 4; ++j) {                            \
      const int c = wave * 4 + j;                                              \
      GLOAD16(A + (size_t)(row0 + c * 8 + srow) * K + (k0) + scol,             \
              &As[buf][c * 8][0]);                                             \
    }                                                                          \
    _Pragma("unroll") for (int j = 0; j < 2; ++j) {                            \
      const int c = wave * 2 + j;                                              \
      GLOAD16(B + (size_t)(col0 + c * 8 + srow) * K + (k0) + scol,             \
              &Bs[buf][c * 8][0]);                                             \
    }                                                                          \
  }

  // prologue: tiles 0 and 1 in flight (6 loads each per wave)
  STAGE3(0, 0)
  STAGE3(1, 64)

  for (int t = 0; t < nt; ++t) {
    const int cur = t % 3;
    // issue tile t+2 into buf (t+2)%3 (its previous readers done at t-1's bar2)
    if (t + 2 < nt) STAGE3((t + 2) % 3, (t + 2) << 6)

    // certify tile t's own 6 loads: keep newer tiles' loads in flight
    if (t + 2 < nt) {
      asm volatile("s_waitcnt vmcnt(12)" ::: "memory");
    } else if (t + 1 < nt) {
      asm volatile("s_waitcnt vmcnt(6)" ::: "memory");
    } else {
      asm volatile("s_waitcnt vmcnt(0)" ::: "memory");
    }
    __builtin_amdgcn_sched_barrier(0);
    __builtin_amdgcn_s_barrier();   // all waves certified -> buf cur readable

    const char* Ab = (const char*)&As[cur][0][0];
    const char* Bb = (const char*)&Bs[cur][0][0];
    __builtin_amdgcn_s_setprio(1);
#pragma unroll
    for (int kk = 0; kk < 2; ++kk) {
      const int co = (kk * 64 + l16 * 16) ^ ((l15 & 7) << 4);
      short8 a[8], b[2];
#pragma unroll
      for (int m = 0; m < 8; ++m)
        a[m] = *(const short8*)(Ab + (wm * 128 + m * 16 + l15) * 128 + co);
#pragma unroll
      for (int n = 0; n < 2; ++n)
        b[n] = *(const short8*)(Bb + (wn * 32 + n * 16 + l15) * 128 + co);
#pragma unroll
      for (int m = 0; m < 8; ++m)
#pragma unroll
        for (int n = 0; n < 2; ++n)
          acc[m][n] =
              __builtin_amdgcn_mfma_f32_16x16x32_bf16(a[m], b[n], acc[m][n], 0, 0, 0);
    }
    __builtin_amdgcn_s_setprio(0);
    __builtin_amdgcn_s_barrier();   // reads of buf cur done before its reuse
  }
#undef STAGE3

#pragma unroll
  for (int m = 0; m < 8; ++m) {
    const int row = row0 + wm * 128 + m * 16 + l16 * 4;
#pragma unroll
    for (int n = 0; n < 2; ++n) {
      const int col = col0 + wn * 32 + n * 16 + l15;
      float bv = 0.f;
      if (OUTF32) bv = bias[col];
#pragma unroll
      for (int r = 0; r < 4; ++r) {
        const float v = acc[m][n][r] + bv;
        if (OUTF32)
          ((float*)Cout)[(size_t)(row + r) * N + col] = v;
        else
          ((unsigned short*)Cout)[(size_t)(row + r) * N + col] = f2bf(v);
      }
    }
  }
}

// ---------------- causal flash attention: in-register P (frozen R11) -------
__device__ __forceinline__ int kvperm(int slot) {
  const int s = slot >> 4, l = (slot >> 2) & 3, rr = slot & 3;
  return 32 * (s & 1) + 8 * l + 4 * (s >> 1) + rr;
}

__global__ __launch_bounds__(512) void attn_fwd(
    const unsigned short* __restrict__ QKV, unsigned short* __restrict__ AO) {
  const int S = 2048, LD = 3072;
  const int qt = gridDim.x - 1 - blockIdx.x;  // long blocks first
  const int bh = blockIdx.y, b = bh >> 4, h = bh & 15;
  const int tid = threadIdx.x, wave = tid >> 6, lane = tid & 63;
  const int l15 = lane & 15, l16 = lane >> 4;
  const int q0 = qt * 128;

  __shared__ __align__(16) char KsB[2][64 * 128];
  __shared__ __align__(16) char VTB[2][64 * 128];

  const unsigned short* qptr =
      QKV + (size_t)(b * S + q0 + wave * 16 + l15) * LD + h * 64 + l16 * 8;
  short8 qf[2];
  qf[0] = *(const short8*)(qptr);
  qf[1] = *(const short8*)(qptr + 32);

  const int krow = lane >> 3;
  const int kcol = (((lane & 7) ^ (lane >> 3)) & 7) * 8;
  int kvp[2];
#pragma unroll
  for (int i = 0; i < 2; ++i)
    kvp[i] = kvperm(((wave - 4) * 2 + i) * 8 + krow);
  const int vp_ = tid & 31, vd0 = ((tid >> 5) & 7) * 8;  // waves 0-3

  float mrow = -1e30f, lsum = 0.f;
  f32x4 accO[4] = {};
  const int nkv = 2 * qt + 2;
  const int koff8 = 8 * l16;

  {
    if (wave >= 4) {
#pragma unroll
      for (int i = 0; i < 2; ++i) {
        const int c = (wave - 4) * 2 + i;
        const unsigned short* gp =
            QKV + (size_t)(b * S + kvp[i]) * LD + 1024 + h * 64 + kcol;
        GLOAD16(gp, KsB[0] + c * 1024);
      }
    } else {
      const unsigned short* vp =
          QKV + (size_t)(b * S + 2 * vp_) * LD + 2048 + h * 64 + vd0;
      short8 va = *(const short8*)vp;
      short8 vb = *(const short8*)(vp + LD);
      uint4 vaw = __builtin_bit_cast(uint4, va);
      uint4 vbw = __builtin_bit_cast(uint4, vb);
      const unsigned int aw[4] = {vaw.x, vaw.y, vaw.z, vaw.w};
      const unsigned int bw[4] = {vbw.x, vbw.y, vbw.z, vbw.w};
#pragma unroll
      for (int w = 0; w < 4; ++w) {
        unsigned int e = __builtin_amdgcn_perm(bw[w], aw[w], 0x05040100u);
        unsigned int o = __builtin_amdgcn_perm(bw[w], aw[w], 0x07060302u);
        *(unsigned int*)(VTB[0] + (((vd0 + 2 * w) * 128 + 4 * vp_) ^ ((2 * w) << 4))) = e;
        *(unsigned int*)(VTB[0] + (((vd0 + 2 * w + 1) * 128 + 4 * vp_) ^ ((2 * w + 1) << 4))) = o;
      }
    }
  }
  __syncthreads();

  for (int t = 0; t < nkv; ++t) {
    const int cur = t & 1, kv0 = t * 64;

    f32x4 accS[4] = {};
#pragma unroll
    for (int sub = 0; sub < 4; ++sub) {
      const int rw = sub * 16 + l15;
#pragma unroll
      for (int kk = 0; kk < 2; ++kk) {
        short8 kf = *(const short8*)(KsB[cur] + rw * 128 +
                                     ((kk * 64 + l16 * 16) ^ ((l15 & 7) << 4)));
        accS[sub] =
            __builtin_amdgcn_mfma_f32_16x16x32_bf16(kf, qf[kk], accS[sub], 0, 0, 0);
      }
    }

    short8 va, vb;
    const bool pre = (t + 1 < nkv);
    if (pre) {
      const int kvn = kv0 + 64;
      if (wave >= 4) {
#pragma unroll
        for (int i = 0; i < 2; ++i) {
          const int c = (wave - 4) * 2 + i;
          const unsigned short* gp =
              QKV + (size_t)(b * S + kvn + kvp[i]) * LD + 1024 + h * 64 + kcol;
          GLOAD16(gp, KsB[cur ^ 1] + c * 1024);
        }
      } else {
        const unsigned short* vp =
            QKV + (size_t)(b * S + kvn + 2 * vp_) * LD + 2048 + h * 64 + vd0;
        va = *(const short8*)vp;
        vb = *(const short8*)(vp + LD);
      }
    }

    const bool nm = (kv0 + 63 > q0 + wave * 16);
    float mx = -1e30f;
    if (nm) {
      const int qabs = q0 + wave * 16 + l15;
#pragma unroll
      for (int sub = 0; sub < 4; ++sub) {
        const int kbase = kv0 + 32 * (sub & 1) + 4 * (sub >> 1) + koff8;
#pragma unroll
        for (int r = 0; r < 4; ++r) {
          float s = accS[sub][r];
          if (kbase + r > qabs) s = -1e30f;
          accS[sub][r] = s;
          mx = fmaxf(mx, s);
        }
      }
    } else {
#pragma unroll
      for (int sub = 0; sub < 4; ++sub)
#pragma unroll
        for (int r = 0; r < 4; ++r) mx = fmaxf(mx, accS[sub][r]);
    }
    mx = fmaxf(mx, __shfl_xor(mx, 16));
    mx = fmaxf(mx, __shfl_xor(mx, 32));

    if (__any(mx > mrow + 8.0f)) {
      const float mnew = fmaxf(mrow, mx);
      const float alpha = exp2f(mrow - mnew);
      mrow = mnew;
      lsum *= alpha;
#pragma unroll
      for (int sd = 0; sd < 4; ++sd)
#pragma unroll
        for (int r = 0; r < 4; ++r) accO[sd][r] *= alpha;
    }

    float rs = 0.f;
#pragma unroll
    for (int sub = 0; sub < 4; ++sub)
#pragma unroll
      for (int r = 0; r < 4; ++r) {
        const float pv = exp2f(accS[sub][r] - mrow);
        accS[sub][r] = pv;
        rs += pv;
      }
    rs += __shfl_xor(rs, 16);
    rs += __shfl_xor(rs, 32);
    lsum += rs;

    short8 pf[2];
#pragma unroll
    for (int kk = 0; kk < 2; ++kk) {
      unsigned int w0, w1, w2, w3;
      asm("v_cvt_pk_bf16_f32 %0, %1, %2" : "=v"(w0) : "v"(accS[kk][0]), "v"(accS[kk][1]));
      asm("v_cvt_pk_bf16_f32 %0, %1, %2" : "=v"(w1) : "v"(accS[kk][2]), "v"(accS[kk][3]));
      asm("v_cvt_pk_bf16_f32 %0, %1, %2" : "=v"(w2) : "v"(accS[kk + 2][0]), "v"(accS[kk + 2][1]));
      asm("v_cvt_pk_bf16_f32 %0, %1, %2" : "=v"(w3) : "v"(accS[kk + 2][2]), "v"(accS[kk + 2][3]));
      uint4 u = {w0, w1, w2, w3};
      pf[kk] = __builtin_bit_cast(short8, u);
    }

    if (pre && wave < 4) {
      uint4 vaw = __builtin_bit_cast(uint4, va);
      uint4 vbw = __builtin_bit_cast(uint4, vb);
      const unsigned int aw[4] = {vaw.x, vaw.y, vaw.z, vaw.w};
      const unsigned int bw[4] = {vbw.x, vbw.y, vbw.z, vbw.w};
#pragma unroll
      for (int w = 0; w < 4; ++w) {
        unsigned int e = __builtin_amdgcn_perm(bw[w], aw[w], 0x05040100u);
        unsigned int o = __builtin_amdgcn_perm(bw[w], aw[w], 0x07060302u);
        *(unsigned int*)(VTB[cur ^ 1] +
                         (((vd0 + 2 * w) * 128 + 4 * vp_) ^ ((2 * w) << 4))) = e;
        *(unsigned int*)(VTB[cur ^ 1] +
                         (((vd0 + 2 * w + 1) * 128 + 4 * vp_) ^ ((2 * w + 1) << 4))) = o;
      }
    }

#pragma unroll
    for (int kk = 0; kk < 2; ++kk) {
#pragma unroll
      for (int sd = 0; sd < 4; ++sd) {
        short8 vf = *(const short8*)(VTB[cur] + (sd * 16 + l15) * 128 +
                                     ((kk * 64 + l16 * 16) ^ ((l15 & 7) << 4)));
        accO[sd] =
            __builtin_amdgcn_mfma_f32_16x16x32_bf16(vf, pf[kk], accO[sd], 0, 0, 0);
      }
    }
    __syncthreads();
  }

  const float inv = __builtin_amdgcn_rcpf(lsum);
  unsigned short* aop =
      AO + (size_t)(b * S + q0 + wave * 16 + l15) * 1024 + h * 64;
#pragma unroll
  for (int sd = 0; sd < 4; ++sd) {
    const int d = sd * 16 + l16 * 4;
    unsigned int w0, w1;
    float o0 = accO[sd][0] * inv, o1 = accO[sd][1] * inv;
    float o2 = accO[sd][2] * inv, o3 = accO[sd][3] * inv;
    asm("v_cvt_pk_bf16_f32 %0, %1, %2" : "=v"(w0) : "v"(o0), "v"(o1));
    asm("v_cvt_pk_bf16_f32 %0, %1, %2" : "=v"(w1) : "v"(o2), "v"(o3));
    *(unsigned int*)(aop + d) = w0;
    *(unsigned int*)(aop + d + 2) = w1;
  }
}

// ---------------- launch ----------------
extern "C" void kernel_launch(void* const* d_in, const int* in_sizes, int n_in,
                              void* d_out, int out_size, void* d_ws,
                              size_t ws_size, hipStream_t stream) {
  const float* x = (const float*)d_in[0];
  const float* Wq = (const float*)d_in[1];
  const float* Wk = (const float*)d_in[2];
  const float* Wv = (const float*)d_in[3];
  const float* Wo = (const float*)d_in[4];
  const float* bo = (const float*)d_in[5];

  char* ws = (char*)d_ws;
  unsigned short* xb = (unsigned short*)(ws);                        // 16 MB
  unsigned short* Wqkv = (unsigned short*)(ws + (size_t)(16 << 20)); // 6 MB
  unsigned short* Wob = (unsigned short*)(ws + (size_t)(22 << 20));  // 2 MB
  unsigned short* QKV = (unsigned short*)(ws + (size_t)(24 << 20));  // 48 MB
  unsigned short* AO = (unsigned short*)(ws + (size_t)(72 << 20));   // 16 MB

  const int M = 8192, D = 1024;
  const float QSCALE = 0.125f * 1.44269504088896340736f;  // 1/sqrt(dk)*log2(e)

  cvt_f32_bf16<<<M * D / 2048, 256, 0, stream>>>(x, xb, M * D, 1.0f);
  dim3 gw(D * D / 2048, 4);
  cvt_w4<<<gw, 256, 0, stream>>>(Wq, Wk, Wv, Wo, Wqkv, Wob, D * D, QSCALE);

  // QKV projection: 256x128 tiles -> grid 32*24 = 768 (3.0 rounds exact)
  gemm_nt3<0><<<(M / 256) * (3072 / 128), 512, 0, stream>>>(
      xb, Wqkv, QKV, nullptr, M, 3072, D, 3072 / 128);

  // attention: QBLK=128 -> grid (16, 64), 512 threads
  dim3 g2(16, 64);
  attn_fwd<<<g2, 512, 0, stream>>>(QKV, AO);

  // O projection: 256x128 tiles -> grid 32*8 = 256 (1.0 rounds exact)
  gemm_nt3<1><<<(M / 256) * (D / 128), 512, 0, stream>>>(
      AO, Wob, d_out, bo, M, D, D, D / 128);
}